// Round 2
// baseline (5905.666 us; speedup 1.0000x reference)
//
#include <hip/hip_runtime.h>
#include <hip/hip_bf16.h>

typedef __bf16 bfr;
typedef bfr v8bf __attribute__((ext_vector_type(8)));
typedef float v4f __attribute__((ext_vector_type(4)));

static constexpr int Bn = 64, H = 256, D = 768;
static constexpr int NR = 100000, ER = 400000;
static constexpr int NC = 100000, EC = 300000, G = 512;

// ---------------- utility kernels ----------------
__global__ void fill_f32(float* p, float v, int n) {
  int i = blockIdx.x * blockDim.x + threadIdx.x;
  if (i < n) p[i] = v;
}

// W f32 [K,N] -> Wt bf16 [N,K]
__global__ void transpose_w(const float* __restrict__ W, bfr* __restrict__ Wt,
                            int K, int N) {
  int i = blockIdx.x * blockDim.x + threadIdx.x;
  if (i >= K * N) return;
  int k = i / N, n = i - k * N;
  Wt[(size_t)n * K + k] = (bfr)W[i];
}

// ---------------- GEMM ----------------
// C[M,N=256] = A[M,K] @ B[K,N]; Bt = bf16 B^T [N,K]. One wave -> 16 rows.
// mfma_f32_16x16x32_bf16 layouts (m89/m91-verified):
//   A frag: A[m=lane&15][k=quad*8+j]; B frag: B[k=quad*8+j][n=lane&15]
//   D:      D[row=quad*4+r][col=lane&15]
template<typename TA>
__launch_bounds__(256)
__global__ void gemm_k(const TA* __restrict__ A, const bfr* __restrict__ Bt,
                       bfr* __restrict__ Cb, float* __restrict__ Cf,
                       int M, int K, int ldc, int col0) {
  int wid = (int)((blockIdx.x * 256u + threadIdx.x) >> 6);
  int m0 = wid * 16;
  if (m0 >= M) return;
  int lane = threadIdx.x & 63;
  int mrow = lane & 15;
  int quad = lane >> 4;
  const TA* Ap = A + (size_t)(m0 + mrow) * K + quad * 8;
  const bfr* Bp = Bt + (size_t)mrow * K + quad * 8;
  v4f acc[16] = {};
  for (int k0 = 0; k0 < K; k0 += 32) {
    v8bf a;
    if constexpr (sizeof(TA) == 4) {   // f32 A: load 2x float4, convert
      const float4* p = (const float4*)(Ap + k0);
      float4 x = p[0], y = p[1];
      a[0] = (bfr)x.x; a[1] = (bfr)x.y; a[2] = (bfr)x.z; a[3] = (bfr)x.w;
      a[4] = (bfr)y.x; a[5] = (bfr)y.y; a[6] = (bfr)y.z; a[7] = (bfr)y.w;
    } else {                            // bf16 A: one 16B load
      a = *(const v8bf*)(Ap + k0);
    }
#pragma unroll
    for (int nt = 0; nt < 16; ++nt) {
      v8bf b = *(const v8bf*)(Bp + (size_t)nt * 16 * K + k0);
      acc[nt] = __builtin_amdgcn_mfma_f32_16x16x32_bf16(a, b, acc[nt], 0, 0, 0);
    }
  }
#pragma unroll
  for (int nt = 0; nt < 16; ++nt) {
#pragma unroll
    for (int r = 0; r < 4; ++r) {
      int row = m0 + quad * 4 + r;
      int col = col0 + nt * 16 + mrow;
      float v = acc[nt][r];
      if (Cf) Cf[(size_t)row * ldc + col] = v;
      else    Cb[(size_t)row * ldc + col] = (bfr)v;
    }
  }
}

// ---------------- GCN pieces ----------------
__global__ void deg_count(const int* __restrict__ dst, float* deg, int E) {
  int e = blockIdx.x * blockDim.x + threadIdx.x;
  if (e < E) atomicAdd(deg + dst[e], 1.0f);
}
__global__ void deg_finish(float* dinv, int n) {
  int i = blockIdx.x * blockDim.x + threadIdx.x;
  if (i < n) dinv[i] = rsqrtf(dinv[i]);
}

// C[i][j] = h[i][j] * dinv[i]^2  (self-loop term; zero-inits accumulator)
__global__ void selfloop_init(const bfr* __restrict__ h, const float* __restrict__ dinv,
                              float* __restrict__ C, int n) {
  int idx = blockIdx.x * blockDim.x + threadIdx.x;
  if (idx >= n) return;
  int i = idx >> 8;
  float di = dinv[i];
  C[idx] = (float)h[idx] * di * di;
}

// one wave per edge: C[dst] += h[src] * dinv[src]*dinv[dst]
__launch_bounds__(256)
__global__ void edge_scatter(const bfr* __restrict__ h, const int* __restrict__ src,
                             const int* __restrict__ dst, const float* __restrict__ dinv,
                             float* __restrict__ C, int E) {
  int wid = (int)((blockIdx.x * 256u + threadIdx.x) >> 6);
  if (wid >= E) return;
  int lane = threadIdx.x & 63;
  int s = src[wid], d = dst[wid];
  float w = dinv[s] * dinv[d];
  const unsigned* hp = (const unsigned*)(h + (size_t)s * H);
  float* cp = C + (size_t)d * H;
#pragma unroll
  for (int it = 0; it < 2; ++it) {
    int j = it * 64 + lane;   // index into 128 packed bf16x2 words
    unsigned v = hp[j];
    float f0 = __uint_as_float(v << 16);
    float f1 = __uint_as_float(v & 0xFFFF0000u);
    atomicAdd(cp + j * 2,     w * f0);
    atomicAdd(cp + j * 2 + 1, w * f1);
  }
}

__global__ void relu_cast(const float* __restrict__ C, bfr* __restrict__ A, int n) {
  int idx = blockIdx.x * blockDim.x + threadIdx.x;
  if (idx < n) A[idx] = (bfr)fmaxf(C[idx], 0.0f);
}

// ---------------- pooling ----------------
__global__ void pool_add(const float* __restrict__ Cv, const int* __restrict__ seg,
                         float* __restrict__ out, int ldo, int col0, int n) {
  int idx = blockIdx.x * blockDim.x + threadIdx.x;
  if (idx >= n) return;
  int i = idx >> 8, j = idx & 255;
  atomicAdd(out + (size_t)seg[i] * ldo + col0 + j, Cv[idx]);
}
__global__ void seg_count(const int* __restrict__ seg, float* cnt, int n) {
  int i = blockIdx.x * blockDim.x + threadIdx.x;
  if (i < n) atomicAdd(cnt + seg[i], 1.0f);
}
__global__ void pool_div(float* __restrict__ out, const float* __restrict__ cnt,
                         int ldo, int col0, int n) {
  int idx = blockIdx.x * blockDim.x + threadIdx.x;
  if (idx >= n) return;
  int r = idx >> 8, j = idx & 255;
  out[(size_t)r * ldo + col0 + j] *= (1.0f / fmaxf(cnt[r], 1.0f));
}

// ---------------- head: MLP + log_softmax + loss (all f32) ----------------
__launch_bounds__(256)
__global__ void final_mlp(const float* __restrict__ reps, const float* __restrict__ W1,
                          const float* __restrict__ b1, const float* __restrict__ W2,
                          const float* __restrict__ b2, const int* __restrict__ label,
                          float* __restrict__ out, float* __restrict__ loss_acc) {
  __shared__ float r[5 * H];
  __shared__ float h[H];
  __shared__ float pr[2];
  int b = blockIdx.x;
  int t = threadIdx.x;
  for (int i = t; i < 5 * H; i += 256) r[i] = reps[(size_t)b * (5 * H) + i];
  __syncthreads();
  float acc = b1[t];
  for (int k = 0; k < 5 * H; ++k) acc += r[k] * W1[(size_t)k * H + t];
  h[t] = fmaxf(acc, 0.0f);
  __syncthreads();
  if (t < 2) {
    float p = b2[t];
    for (int k = 0; k < H; ++k) p += h[k] * W2[k * 2 + t];
    pr[t] = p;
  }
  __syncthreads();
  if (t == 0) {
    float p0 = pr[0], p1 = pr[1];
    out[b * 2 + 0] = p0;
    out[b * 2 + 1] = p1;
    float m = fmaxf(p0, p1);
    float lse = m + logf(expf(p0 - m) + expf(p1 - m));
    float lp = (label[b] ? p1 : p0) - lse;
    atomicAdd(loss_acc, -lp * (1.0f / 64.0f));
  }
}

__global__ void loss_write(const float* loss_acc, float* out) {
  out[128] = *loss_acc;
}

// ---------------- host ----------------
extern "C" void kernel_launch(void* const* d_in, const int* in_sizes, int n_in,
                              void* d_out, int out_size, void* d_ws, size_t ws_size,
                              hipStream_t stream) {
  const float* content   = (const float*)d_in[0];
  const float* video     = (const float*)d_in[1];
  const float* image     = (const float*)d_in[2];
  const float* repost_x  = (const float*)d_in[3];
  const float* comment_x = (const float*)d_in[4];
  const float* W_text    = (const float*)d_in[5];
  const float* W_video   = (const float*)d_in[6];
  const float* W_image   = (const float*)d_in[7];
  const float* Wr1       = (const float*)d_in[8];
  const float* Wr2       = (const float*)d_in[9];
  const float* Wc1       = (const float*)d_in[10];
  const float* Wc2       = (const float*)d_in[11];
  const float* W1        = (const float*)d_in[12];
  const float* b1        = (const float*)d_in[13];
  const float* W2        = (const float*)d_in[14];
  const float* b2        = (const float*)d_in[15];
  const int* r_edge      = (const int*)d_in[16];
  const int* r_batch     = (const int*)d_in[17];
  const int* c_edge      = (const int*)d_in[18];
  const int* c_batch     = (const int*)d_in[19];
  const int* cg_batch    = (const int*)d_in[20];
  const int* label       = (const int*)d_in[21];
  float* out = (float*)d_out;

  char* wsb = (char*)d_ws;
  size_t off = 0;
  auto alloc = [&](size_t bytes) -> void* {
    void* p = wsb + off;
    off += (bytes + 255) & ~(size_t)255;
    return p;
  };
  const size_t NH = (size_t)NR * H;           // == NC*H
  bfr*   bufA   = (bfr*)alloc(NH * 2);        // projected x / relu output (bf16)
  bfr*   bufB   = (bfr*)alloc(NH * 2);        // conv gemm output h (bf16)
  float* bufC   = (float*)alloc(NH * 4);      // aggregation accumulator (f32)
  float* dinv   = (float*)alloc(NR * 4);
  bfr*   Wt_t   = (bfr*)alloc((size_t)D * H * 2);
  bfr*   Wt_v   = (bfr*)alloc((size_t)D * H * 2);
  bfr*   Wt_i   = (bfr*)alloc((size_t)D * H * 2);
  bfr*   Wt_r1  = (bfr*)alloc((size_t)H * H * 2);
  bfr*   Wt_r2  = (bfr*)alloc((size_t)H * H * 2);
  bfr*   Wt_c1  = (bfr*)alloc((size_t)H * H * 2);
  bfr*   Wt_c2  = (bfr*)alloc((size_t)H * H * 2);
  float* reps   = (float*)alloc((size_t)Bn * 5 * H * 4);
  float* graphs = (float*)alloc((size_t)G * H * 4);
  float* cntA   = (float*)alloc(G * 4);
  float* cntB   = (float*)alloc(Bn * 4);
  float* cntC   = (float*)alloc(Bn * 4);
  float* lossw  = (float*)alloc(4);
  (void)ws_size; (void)n_in; (void)in_sizes; (void)out_size;

  const int T = 256;
  auto cdiv = [](int a, int b) { return (a + b - 1) / b; };

  // weight transposes (f32 -> bf16^T)
  transpose_w<<<cdiv(D * H, T), T, 0, stream>>>(W_text, Wt_t, D, H);
  transpose_w<<<cdiv(D * H, T), T, 0, stream>>>(W_video, Wt_v, D, H);
  transpose_w<<<cdiv(D * H, T), T, 0, stream>>>(W_image, Wt_i, D, H);
  transpose_w<<<cdiv(H * H, T), T, 0, stream>>>(Wr1, Wt_r1, H, H);
  transpose_w<<<cdiv(H * H, T), T, 0, stream>>>(Wr2, Wt_r2, H, H);
  transpose_w<<<cdiv(H * H, T), T, 0, stream>>>(Wc1, Wt_c1, H, H);
  transpose_w<<<cdiv(H * H, T), T, 0, stream>>>(Wc2, Wt_c2, H, H);

  // zero accumulated buffers (own kernels; ws is re-poisoned each launch)
  fill_f32<<<cdiv(Bn * 5 * H, T), T, 0, stream>>>(reps, 0.0f, Bn * 5 * H);
  fill_f32<<<cdiv(G * H, T), T, 0, stream>>>(graphs, 0.0f, G * H);
  fill_f32<<<1, T, 0, stream>>>(cntA, 0.0f, G);
  fill_f32<<<1, T, 0, stream>>>(cntB, 0.0f, Bn);
  fill_f32<<<1, T, 0, stream>>>(cntC, 0.0f, Bn);
  fill_f32<<<1, 1, 0, stream>>>(lossw, 0.0f, 1);

  auto gemm_f = [&](const float* A, const bfr* Bt, bfr* Cb, float* Cf,
                    int M, int K, int ldc, int col0) {
    gemm_k<float><<<cdiv(M / 16, 4), T, 0, stream>>>(A, Bt, Cb, Cf, M, K, ldc, col0);
  };
  auto gemm_b = [&](const bfr* A, const bfr* Bt, bfr* Cb, float* Cf,
                    int M, int K, int ldc, int col0) {
    gemm_k<bfr><<<cdiv(M / 16, 4), T, 0, stream>>>(A, Bt, Cb, Cf, M, K, ldc, col0);
  };

  // modality GEMMs straight into reps (f32)
  gemm_f(content, Wt_t, nullptr, reps, Bn, D, 5 * H, 0 * H);
  gemm_f(video,   Wt_v, nullptr, reps, Bn, D, 5 * H, 3 * H);
  gemm_f(image,   Wt_i, nullptr, reps, Bn, D, 5 * H, 4 * H);

  const int NE = NR * H;  // elementwise count (same for NC)

  // ---- repost branch ----
  gemm_f(repost_x, Wt_t, bufA, nullptr, NR, D, H, 0);
  fill_f32<<<cdiv(NR, T), T, 0, stream>>>(dinv, 1.0f, NR);
  deg_count<<<cdiv(ER, T), T, 0, stream>>>(r_edge + ER, dinv, ER);
  deg_finish<<<cdiv(NR, T), T, 0, stream>>>(dinv, NR);
  // conv1
  gemm_b(bufA, Wt_r1, bufB, nullptr, NR, H, H, 0);
  selfloop_init<<<cdiv(NE, T), T, 0, stream>>>(bufB, dinv, bufC, NE);
  edge_scatter<<<cdiv(ER, 4), T, 0, stream>>>(bufB, r_edge, r_edge + ER, dinv, bufC, ER);
  relu_cast<<<cdiv(NE, T), T, 0, stream>>>(bufC, bufA, NE);
  // conv2
  gemm_b(bufA, Wt_r2, bufB, nullptr, NR, H, H, 0);
  selfloop_init<<<cdiv(NE, T), T, 0, stream>>>(bufB, dinv, bufC, NE);
  edge_scatter<<<cdiv(ER, 4), T, 0, stream>>>(bufB, r_edge, r_edge + ER, dinv, bufC, ER);
  // mean pool -> reps[:, H:2H]
  seg_count<<<cdiv(NR, T), T, 0, stream>>>(r_batch, cntB, NR);
  pool_add<<<cdiv(NE, T), T, 0, stream>>>(bufC, r_batch, reps, 5 * H, 1 * H, NE);
  pool_div<<<cdiv(Bn * H, T), T, 0, stream>>>(reps, cntB, 5 * H, 1 * H, Bn * H);

  // ---- comment branch ----
  gemm_f(comment_x, Wt_t, bufA, nullptr, NC, D, H, 0);
  fill_f32<<<cdiv(NC, T), T, 0, stream>>>(dinv, 1.0f, NC);
  deg_count<<<cdiv(EC, T), T, 0, stream>>>(c_edge + EC, dinv, EC);
  deg_finish<<<cdiv(NC, T), T, 0, stream>>>(dinv, NC);
  // conv1
  gemm_b(bufA, Wt_c1, bufB, nullptr, NC, H, H, 0);
  selfloop_init<<<cdiv(NE, T), T, 0, stream>>>(bufB, dinv, bufC, NE);
  edge_scatter<<<cdiv(EC, 4), T, 0, stream>>>(bufB, c_edge, c_edge + EC, dinv, bufC, EC);
  relu_cast<<<cdiv(NE, T), T, 0, stream>>>(bufC, bufA, NE);
  // conv2
  gemm_b(bufA, Wt_c2, bufB, nullptr, NC, H, H, 0);
  selfloop_init<<<cdiv(NE, T), T, 0, stream>>>(bufB, dinv, bufC, NE);
  edge_scatter<<<cdiv(EC, 4), T, 0, stream>>>(bufB, c_edge, c_edge + EC, dinv, bufC, EC);
  // pool nodes -> graphs
  seg_count<<<cdiv(NC, T), T, 0, stream>>>(c_batch, cntA, NC);
  pool_add<<<cdiv(NE, T), T, 0, stream>>>(bufC, c_batch, graphs, H, 0, NE);
  pool_div<<<cdiv(G * H, T), T, 0, stream>>>(graphs, cntA, H, 0, G * H);
  // pool graphs -> reps[:, 2H:3H]
  seg_count<<<cdiv(G, T), T, 0, stream>>>(cg_batch, cntC, G);
  pool_add<<<cdiv(G * H, T), T, 0, stream>>>(graphs, cg_batch, reps, 5 * H, 2 * H, G * H);
  pool_div<<<cdiv(Bn * H, T), T, 0, stream>>>(reps, cntC, 5 * H, 2 * H, Bn * H);

  // ---- head ----
  final_mlp<<<Bn, T, 0, stream>>>(reps, W1, b1, W2, b2, label, out, lossw);
  loss_write<<<1, 1, 0, stream>>>(lossw, out);
}

// Round 3
// 2707.259 us; speedup vs baseline: 2.1814x; 2.1814x over previous
//
#include <hip/hip_runtime.h>
#include <hip/hip_bf16.h>

typedef __bf16 bfr;
typedef bfr v8bf __attribute__((ext_vector_type(8)));
typedef bfr v4bf __attribute__((ext_vector_type(4)));
typedef float v4f __attribute__((ext_vector_type(4)));

static constexpr int Bn = 64, H = 256, D = 768;
static constexpr int NR = 100000, ER = 400000;
static constexpr int NC = 100000, EC = 300000, G = 512;
static constexpr int SCAN_CH = 1024;  // elements per scan block

// ---------------- utility ----------------
__global__ void fill_f32(float* p, float v, int n) {
  int i = blockIdx.x * blockDim.x + threadIdx.x;
  if (i < n) p[i] = v;
}
__global__ void fill_i32(int* p, int v, int n) {
  int i = blockIdx.x * blockDim.x + threadIdx.x;
  if (i < n) p[i] = v;
}

// W f32 [K,N] -> Wt bf16 [N,K]
__global__ void transpose_w(const float* __restrict__ W, bfr* __restrict__ Wt,
                            int K, int N) {
  int i = blockIdx.x * blockDim.x + threadIdx.x;
  if (i >= K * N) return;
  int k = i / N, n = i - k * N;
  Wt[(size_t)n * K + k] = (bfr)W[i];
}

// ---------------- GEMM (N=256, one wave -> 16 rows) ----------------
// mfma_f32_16x16x32_bf16: A[m=lane&15][k=quad*8+j]; B[k=quad*8+j][n=lane&15];
// D[row=quad*4+r][col=lane&15]   (m89/m91-verified layouts)
template<typename TA>
__launch_bounds__(256)
__global__ void gemm_k(const TA* __restrict__ A, const bfr* __restrict__ Bt,
                       bfr* __restrict__ Cb, float* __restrict__ Cf,
                       int M, int K, int ldc, int col0) {
  int wid = (int)((blockIdx.x * 256u + threadIdx.x) >> 6);
  int m0 = wid * 16;
  if (m0 >= M) return;
  int lane = threadIdx.x & 63;
  int mrow = lane & 15;
  int quad = lane >> 4;
  const TA* Ap = A + (size_t)(m0 + mrow) * K + quad * 8;
  const bfr* Bp = Bt + (size_t)mrow * K + quad * 8;
  v4f acc[16] = {};
  for (int k0 = 0; k0 < K; k0 += 32) {
    v8bf a;
    if constexpr (sizeof(TA) == 4) {
      const float4* p = (const float4*)(Ap + k0);
      float4 x = p[0], y = p[1];
      a[0] = (bfr)x.x; a[1] = (bfr)x.y; a[2] = (bfr)x.z; a[3] = (bfr)x.w;
      a[4] = (bfr)y.x; a[5] = (bfr)y.y; a[6] = (bfr)y.z; a[7] = (bfr)y.w;
    } else {
      a = *(const v8bf*)(Ap + k0);
    }
#pragma unroll
    for (int nt = 0; nt < 16; ++nt) {
      v8bf b = *(const v8bf*)(Bp + (size_t)nt * 16 * K + k0);
      acc[nt] = __builtin_amdgcn_mfma_f32_16x16x32_bf16(a, b, acc[nt], 0, 0, 0);
    }
  }
#pragma unroll
  for (int nt = 0; nt < 16; ++nt) {
#pragma unroll
    for (int r = 0; r < 4; ++r) {
      int row = m0 + quad * 4 + r;
      int col = col0 + nt * 16 + mrow;
      float v = acc[nt][r];
      if (Cf) Cf[(size_t)row * ldc + col] = v;
      else    Cb[(size_t)row * ldc + col] = (bfr)v;
    }
  }
}

// ---------------- CSR build ----------------
__global__ void deg_count_i(const int* __restrict__ dst, int* deg, int E) {
  int e = blockIdx.x * blockDim.x + threadIdx.x;
  if (e < E) atomicAdd(deg + dst[e], 1);
}
__global__ void dinv_from_deg(const int* __restrict__ deg, float* dinv, int n) {
  int i = blockIdx.x * blockDim.x + threadIdx.x;
  if (i < n) dinv[i] = rsqrtf((float)deg[i] + 1.0f);  // +1 self loop
}

// hierarchical exclusive scan: deg[n] -> part[n] (chunk-local), bsum per block
__global__ void scan1(const int* __restrict__ deg, int* __restrict__ part,
                      int* __restrict__ bsum, int n) {
  __shared__ int tmp[256];
  int t = threadIdx.x;
  int base = blockIdx.x * SCAN_CH + t * 4;
  int v0 = (base + 0 < n) ? deg[base + 0] : 0;
  int v1 = (base + 1 < n) ? deg[base + 1] : 0;
  int v2 = (base + 2 < n) ? deg[base + 2] : 0;
  int v3 = (base + 3 < n) ? deg[base + 3] : 0;
  int ls = v0 + v1 + v2 + v3;
  tmp[t] = ls;
  __syncthreads();
  for (int o = 1; o < 256; o <<= 1) {
    int vv = (t >= o) ? tmp[t - o] : 0;
    __syncthreads();
    tmp[t] += vv;
    __syncthreads();
  }
  int off = tmp[t] - ls;  // exclusive prefix of this thread's group
  if (base + 0 < n) part[base + 0] = off;
  if (base + 1 < n) part[base + 1] = off + v0;
  if (base + 2 < n) part[base + 2] = off + v0 + v1;
  if (base + 3 < n) part[base + 3] = off + v0 + v1 + v2;
  if (t == 255) bsum[blockIdx.x] = tmp[255];
}
__global__ void scan2(int* bsum, int nb) {  // in-place exclusive
  if (threadIdx.x == 0 && blockIdx.x == 0) {
    int run = 0;
    for (int b = 0; b < nb; ++b) { int s = bsum[b]; bsum[b] = run; run += s; }
  }
}
__global__ void scan3(int* __restrict__ part, const int* __restrict__ bsum,
                      int n, int E) {
  int i = blockIdx.x * blockDim.x + threadIdx.x;
  if (i < n) part[i] += bsum[i / SCAN_CH];
  if (i == n) part[n] = E;
}

__global__ void fill_edges(const int* __restrict__ src, const int* __restrict__ dst,
                           const float* __restrict__ dinv, const int* __restrict__ rp,
                           int* __restrict__ cursor, int* __restrict__ esrc,
                           float* __restrict__ ew, int E) {
  int e = blockIdx.x * blockDim.x + threadIdx.x;
  if (e >= E) return;
  int s = src[e], d = dst[e];
  int pos = rp[d] + atomicAdd(cursor + d, 1);
  esrc[pos] = s;
  ew[pos] = dinv[s] * dinv[d];
}

// ---------------- GCN aggregate (gather, no atomics) ----------------
// one wave per node; lane owns cols [lane*4, lane*4+4)
__device__ __forceinline__ void bf4_to_f32(const ushort4 u, float f[4]) {
  f[0] = __uint_as_float((unsigned)u.x << 16);
  f[1] = __uint_as_float((unsigned)u.y << 16);
  f[2] = __uint_as_float((unsigned)u.z << 16);
  f[3] = __uint_as_float((unsigned)u.w << 16);
}
template<bool RELU>
__launch_bounds__(256)
__global__ void gcn_gather(const bfr* __restrict__ h, const int* __restrict__ rp,
                           const int* __restrict__ esrc, const float* __restrict__ ew,
                           const float* __restrict__ dinv,
                           bfr* __restrict__ outB, float* __restrict__ outF, int N) {
  int node = (int)((blockIdx.x * 256u + threadIdx.x) >> 6);
  if (node >= N) return;
  int lane = threadIdx.x & 63;
  const ushort* hp = (const ushort*)h;
  size_t self = (size_t)node * H + lane * 4;
  float di = dinv[node];
  float w0 = di * di;
  float a[4], f[4];
  bf4_to_f32(*(const ushort4*)(hp + self), f);
  a[0] = f[0] * w0; a[1] = f[1] * w0; a[2] = f[2] * w0; a[3] = f[3] * w0;
  int beg = rp[node], end = rp[node + 1];
  for (int j = beg; j < end; ++j) {
    int s = esrc[j];
    float wj = ew[j];
    bf4_to_f32(*(const ushort4*)(hp + (size_t)s * H + lane * 4), f);
    a[0] += f[0] * wj; a[1] += f[1] * wj; a[2] += f[2] * wj; a[3] += f[3] * wj;
  }
  if (RELU) {
    v4bf o;
    o[0] = (bfr)fmaxf(a[0], 0.0f); o[1] = (bfr)fmaxf(a[1], 0.0f);
    o[2] = (bfr)fmaxf(a[2], 0.0f); o[3] = (bfr)fmaxf(a[3], 0.0f);
    *(v4bf*)(outB + self) = o;
  } else {
    float4 o = make_float4(a[0], a[1], a[2], a[3]);
    *(float4*)(outF + self) = o;
  }
}

// ---------------- pooling: sorted seg -> block per segment, no atomics ----
__global__ void pool_seg(const float* __restrict__ x, const int* __restrict__ seg,
                         int n, float* __restrict__ out, int ldo, int col0) {
  int s = blockIdx.x;
  int t = threadIdx.x;
  int lo = 0, hi = n;
  while (lo < hi) { int m = (lo + hi) >> 1; if (seg[m] < s) lo = m + 1; else hi = m; }
  int beg = lo;
  hi = n;
  while (lo < hi) { int m = (lo + hi) >> 1; if (seg[m] < s + 1) lo = m + 1; else hi = m; }
  int end = lo;
  float a0 = 0, a1 = 0, a2 = 0, a3 = 0;
  int r = beg;
  for (; r + 4 <= end; r += 4) {
    a0 += x[(size_t)(r + 0) * H + t];
    a1 += x[(size_t)(r + 1) * H + t];
    a2 += x[(size_t)(r + 2) * H + t];
    a3 += x[(size_t)(r + 3) * H + t];
  }
  for (; r < end; ++r) a0 += x[(size_t)r * H + t];
  float acc = (a0 + a1) + (a2 + a3);
  out[(size_t)s * ldo + col0 + t] = acc / fmaxf((float)(end - beg), 1.0f);
}

// ---------------- head ----------------
__launch_bounds__(256)
__global__ void final_mlp(const float* __restrict__ reps, const float* __restrict__ W1,
                          const float* __restrict__ b1, const float* __restrict__ W2,
                          const float* __restrict__ b2, const int* __restrict__ label,
                          float* __restrict__ out, float* __restrict__ loss_acc) {
  __shared__ float r[5 * H];
  __shared__ float h[H];
  __shared__ float pr[2];
  int b = blockIdx.x;
  int t = threadIdx.x;
  for (int i = t; i < 5 * H; i += 256) r[i] = reps[(size_t)b * (5 * H) + i];
  __syncthreads();
  float acc = b1[t];
  for (int k = 0; k < 5 * H; ++k) acc += r[k] * W1[(size_t)k * H + t];
  h[t] = fmaxf(acc, 0.0f);
  __syncthreads();
  if (t < 2) {
    float p = b2[t];
    for (int k = 0; k < H; ++k) p += h[k] * W2[k * 2 + t];
    pr[t] = p;
  }
  __syncthreads();
  if (t == 0) {
    float p0 = pr[0], p1 = pr[1];
    out[b * 2 + 0] = p0;
    out[b * 2 + 1] = p1;
    float m = fmaxf(p0, p1);
    float lse = m + logf(expf(p0 - m) + expf(p1 - m));
    float lp = (label[b] ? p1 : p0) - lse;
    atomicAdd(loss_acc, -lp * (1.0f / 64.0f));
  }
}
__global__ void loss_write(const float* loss_acc, float* out) {
  out[128] = *loss_acc;
}

// ---------------- host ----------------
extern "C" void kernel_launch(void* const* d_in, const int* in_sizes, int n_in,
                              void* d_out, int out_size, void* d_ws, size_t ws_size,
                              hipStream_t stream) {
  const float* content   = (const float*)d_in[0];
  const float* video     = (const float*)d_in[1];
  const float* image     = (const float*)d_in[2];
  const float* repost_x  = (const float*)d_in[3];
  const float* comment_x = (const float*)d_in[4];
  const float* W_text    = (const float*)d_in[5];
  const float* W_video   = (const float*)d_in[6];
  const float* W_image   = (const float*)d_in[7];
  const float* Wr1       = (const float*)d_in[8];
  const float* Wr2       = (const float*)d_in[9];
  const float* Wc1       = (const float*)d_in[10];
  const float* Wc2       = (const float*)d_in[11];
  const float* W1        = (const float*)d_in[12];
  const float* b1        = (const float*)d_in[13];
  const float* W2        = (const float*)d_in[14];
  const float* b2        = (const float*)d_in[15];
  const int* r_edge      = (const int*)d_in[16];
  const int* r_batch     = (const int*)d_in[17];
  const int* c_edge      = (const int*)d_in[18];
  const int* c_batch     = (const int*)d_in[19];
  const int* cg_batch    = (const int*)d_in[20];
  const int* label       = (const int*)d_in[21];
  float* out = (float*)d_out;

  char* wsb = (char*)d_ws;
  size_t off = 0;
  auto alloc = [&](size_t bytes) -> void* {
    void* p = wsb + off;
    off += (bytes + 255) & ~(size_t)255;
    return p;
  };
  const size_t NH = (size_t)NR * H;  // == NC*H
  bfr*   bufA    = (bfr*)alloc(NH * 2);
  bfr*   bufB    = (bfr*)alloc(NH * 2);
  float* bufC    = (float*)alloc(NH * 4);
  float* dinv    = (float*)alloc(NR * 4);
  int*   deg     = (int*)alloc(NR * 4);
  int*   cursor  = (int*)alloc(NR * 4);
  int*   row_ptr = (int*)alloc((NR + 1) * 4);
  int*   esrc    = (int*)alloc((size_t)ER * 4);
  float* ew      = (float*)alloc((size_t)ER * 4);
  int*   bsum    = (int*)alloc(128 * 4);
  bfr*   Wt_t    = (bfr*)alloc((size_t)D * H * 2);
  bfr*   Wt_v    = (bfr*)alloc((size_t)D * H * 2);
  bfr*   Wt_i    = (bfr*)alloc((size_t)D * H * 2);
  bfr*   Wt_r1   = (bfr*)alloc((size_t)H * H * 2);
  bfr*   Wt_r2   = (bfr*)alloc((size_t)H * H * 2);
  bfr*   Wt_c1   = (bfr*)alloc((size_t)H * H * 2);
  bfr*   Wt_c2   = (bfr*)alloc((size_t)H * H * 2);
  float* reps    = (float*)alloc((size_t)Bn * 5 * H * 4);
  float* graphs  = (float*)alloc((size_t)G * H * 4);
  float* lossw   = (float*)alloc(4);
  (void)ws_size; (void)n_in; (void)in_sizes; (void)out_size;

  const int T = 256;
  auto cdiv = [](int a, int b) { return (a + b - 1) / b; };

  transpose_w<<<cdiv(D * H, T), T, 0, stream>>>(W_text, Wt_t, D, H);
  transpose_w<<<cdiv(D * H, T), T, 0, stream>>>(W_video, Wt_v, D, H);
  transpose_w<<<cdiv(D * H, T), T, 0, stream>>>(W_image, Wt_i, D, H);
  transpose_w<<<cdiv(H * H, T), T, 0, stream>>>(Wr1, Wt_r1, H, H);
  transpose_w<<<cdiv(H * H, T), T, 0, stream>>>(Wr2, Wt_r2, H, H);
  transpose_w<<<cdiv(H * H, T), T, 0, stream>>>(Wc1, Wt_c1, H, H);
  transpose_w<<<cdiv(H * H, T), T, 0, stream>>>(Wc2, Wt_c2, H, H);
  fill_f32<<<1, 1, 0, stream>>>(lossw, 0.0f, 1);

  auto gemm_f = [&](const float* A, const bfr* Bt, bfr* Cb, float* Cf,
                    int M, int K, int ldc, int col0) {
    gemm_k<float><<<cdiv(M / 16, 4), T, 0, stream>>>(A, Bt, Cb, Cf, M, K, ldc, col0);
  };
  auto gemm_b = [&](const bfr* A, const bfr* Bt, bfr* Cb,
                    int M, int K) {
    gemm_k<bfr><<<cdiv(M / 16, 4), T, 0, stream>>>(A, Bt, Cb, nullptr, M, K, H, 0);
  };
  auto build_csr = [&](const int* edge, int N, int E) {
    int nb = cdiv(N, SCAN_CH);
    fill_i32<<<cdiv(N, T), T, 0, stream>>>(deg, 0, N);
    deg_count_i<<<cdiv(E, T), T, 0, stream>>>(edge + E, deg, E);
    dinv_from_deg<<<cdiv(N, T), T, 0, stream>>>(deg, dinv, N);
    scan1<<<nb, T, 0, stream>>>(deg, row_ptr, bsum, N);
    scan2<<<1, 64, 0, stream>>>(bsum, nb);
    scan3<<<cdiv(N + 1, T), T, 0, stream>>>(row_ptr, bsum, N, E);
    fill_i32<<<cdiv(N, T), T, 0, stream>>>(cursor, 0, N);
    fill_edges<<<cdiv(E, T), T, 0, stream>>>(edge, edge + E, dinv, row_ptr,
                                             cursor, esrc, ew, E);
  };
  auto gather_relu = [&](const bfr* h, bfr* o, int N) {
    gcn_gather<true><<<cdiv(N, 4), T, 0, stream>>>(h, row_ptr, esrc, ew, dinv,
                                                   o, nullptr, N);
  };
  auto gather_f32 = [&](const bfr* h, float* o, int N) {
    gcn_gather<false><<<cdiv(N, 4), T, 0, stream>>>(h, row_ptr, esrc, ew, dinv,
                                                    nullptr, o, N);
  };

  // modality GEMMs straight into reps
  gemm_f(content, Wt_t, nullptr, reps, Bn, D, 5 * H, 0 * H);
  gemm_f(video,   Wt_v, nullptr, reps, Bn, D, 5 * H, 3 * H);
  gemm_f(image,   Wt_i, nullptr, reps, Bn, D, 5 * H, 4 * H);

  // ---- repost branch ----
  gemm_f(repost_x, Wt_t, bufA, nullptr, NR, D, H, 0);
  build_csr(r_edge, NR, ER);
  gemm_b(bufA, Wt_r1, bufB, NR, H);
  gather_relu(bufB, bufA, NR);
  gemm_b(bufA, Wt_r2, bufB, NR, H);
  gather_f32(bufB, bufC, NR);
  pool_seg<<<Bn, H, 0, stream>>>(bufC, r_batch, NR, reps, 5 * H, 1 * H);

  // ---- comment branch ----
  gemm_f(comment_x, Wt_t, bufA, nullptr, NC, D, H, 0);
  build_csr(c_edge, NC, EC);
  gemm_b(bufA, Wt_c1, bufB, NC, H);
  gather_relu(bufB, bufA, NC);
  gemm_b(bufA, Wt_c2, bufB, NC, H);
  gather_f32(bufB, bufC, NC);
  pool_seg<<<G, H, 0, stream>>>(bufC, c_batch, NC, graphs, H, 0);
  pool_seg<<<Bn, H, 0, stream>>>(graphs, cg_batch, G, reps, 5 * H, 2 * H);

  // ---- head ----
  final_mlp<<<Bn, T, 0, stream>>>(reps, W1, b1, W2, b2, label, out, lossw);
  loss_write<<<1, 1, 0, stream>>>(lossw, out);
}